// Round 10
// baseline (302.347 us; speedup 1.0000x reference)
//
#include <hip/hip_runtime.h>
#include <stdint.h>

#define NN 4096
#define NITER 10
#define ROWS 16
#define NBLK 256

// LDS (bytes): KT interleaved [0,131072) | stage 18432 | red 4096 = 153,600
#define STG_OFF  131072
#define RED_OFF  149504

typedef float v2f __attribute__((ext_vector_type(2)));

static __device__ __forceinline__ unsigned short f2bf(float f) {
  union { float f; unsigned int i; } x; x.f = f;
  unsigned int i = x.i;
  i += 0x7FFFu + ((i >> 16) & 1u);
  return (unsigned short)(i >> 16);
}
static __device__ __forceinline__ unsigned int pk2(float a, float b) {
  return (unsigned int)f2bf(a) | ((unsigned int)f2bf(b) << 16);
}
static __device__ __forceinline__ float2 unpk(unsigned int u) {
  union { unsigned int i; float f; } a, b;
  a.i = u << 16; b.i = u & 0xFFFF0000u;
  return make_float2(a.f, b.f);
}
static __device__ __forceinline__ float read_eps(const void* p) {
  float f = *(const float*)p;
  if (f > 1e-4f && f < 1.0f) return f;
  union { unsigned int i; float f; } x;
  x.i = ((unsigned int)*(const unsigned short*)p) << 16;
  return x.f;
}
static __device__ __forceinline__ unsigned long long aload8(const unsigned long long* p) {
  return __hip_atomic_load(p, __ATOMIC_RELAXED, __HIP_MEMORY_SCOPE_AGENT);
}
static __device__ __forceinline__ void astore8(unsigned long long* p, unsigned long long v) {
  __hip_atomic_store(p, v, __ATOMIC_RELAXED, __HIP_MEMORY_SCOPE_AGENT);
}
static __device__ __forceinline__ float4 up4(unsigned int w0, unsigned int w1) {
  float2 a = unpk(w0), b = unpk(w1);
  return make_float4(a.x, a.y, b.x, b.y);
}
// A published u/v bf16x4 word has all 4 halves positive & nonzero.
// 0xAA poison (sign set) and zero-init both register invalid.
static __device__ __forceinline__ bool bad8(unsigned long long x) {
  unsigned lo = (unsigned)x, hi = (unsigned)(x >> 32);
  if ((lo | hi) & 0x80008000u) return true;
  return ((lo & 0xffffu) == 0u) || ((lo >> 16) == 0u) ||
         ((hi & 0xffffu) == 0u) || ((hi >> 16) == 0u);
}
static __device__ __forceinline__ v2f mk2(float a, float b) {
  v2f r; r.x = a; r.y = b; return r;
}
#define FMA2(a, b, c) __builtin_elementwise_fma(a, b, c)

// ---------------------------------------------------------------------------
// Persistent, barrier-FREE: block b owns rows [16b,+16) and cols [16b,+16)
// (XCD-banded). Row-K global+private (L2-resident); col-K^T LDS-resident.
// u/v cross blocks via bf16x4 epoch buffers at the IC; readers spin on the
// data itself (sign/nonzero sentinel) -> pure dataflow pipeline, no barriers.
__global__ __launch_bounds__(256, 1) void sinkhorn_all(
    const float* __restrict__ alpha, const float* __restrict__ beta,
    const float* __restrict__ C, const void* __restrict__ epsp,
    unsigned short* __restrict__ K, unsigned long long* __restrict__ u_ep,
    unsigned long long* __restrict__ v_ep, float* __restrict__ out) {
  __shared__ float4 smem4[9600];             // 153,600 B
  char* sm = (char*)smem4;
  const int t = threadIdx.x, b = blockIdx.x;
  const int wave = t >> 6, lane = t & 63, sw = lane & 7;
  const int own = ((b & 7) << 5) | (b >> 3);
  const int base0 = own * ROWS;              // first owned row AND col
  const float eps = read_eps(epsp);
  const float nie = -1.0f / eps;

  // ---- build row-K (global, private): coalesced C row reads ----
#pragma unroll 2
  for (int r = 0; r < ROWS; ++r) {
    const float4* Crow = (const float4*)(C + (size_t)(base0 + r) * NN) + t * 4;
    float4 c0 = Crow[0], c1 = Crow[1], c2 = Crow[2], c3 = Crow[3];
    uint4 k0, k1;
    k0.x = pk2(__expf(c0.x * nie), __expf(c0.y * nie));
    k0.y = pk2(__expf(c0.z * nie), __expf(c0.w * nie));
    k0.z = pk2(__expf(c1.x * nie), __expf(c1.y * nie));
    k0.w = pk2(__expf(c1.z * nie), __expf(c1.w * nie));
    k1.x = pk2(__expf(c2.x * nie), __expf(c2.y * nie));
    k1.y = pk2(__expf(c2.z * nie), __expf(c2.w * nie));
    k1.z = pk2(__expf(c3.x * nie), __expf(c3.y * nie));
    k1.w = pk2(__expf(c3.z * nie), __expf(c3.w * nie));
    uint4* Krow = (uint4*)(K + (size_t)(base0 + r) * NN);
    Krow[t * 2] = k0;
    Krow[t * 2 + 1] = k1;
  }

  // ---- build K^T strip in LDS (lane-linear interleave) ----
  {
    const int p = t & 3, rb = t >> 2, cb = p * 4;
#pragma unroll 1
    for (int q = 0; q < 64; q += 8) {
      float4 cv[8];
#pragma unroll
      for (int z = 0; z < 8; ++z)
        cv[z] = *(const float4*)(C + (size_t)((q + z) * 64 + rb) * NN + base0 + cb);
#pragma unroll
      for (int z = 0; z < 8; ++z) {
        int n = (q + z) * 64 + rb;
        int u16 = ((n >> 10) * 8 + ((n >> 3) & 7)) * 256 + ((n >> 6) & 15) * 16;
        int jo = (n & 7) * 2;
        *(unsigned short*)(sm + (size_t)(u16 + cb + 0) * 16 + jo) = f2bf(__expf(cv[z].x * nie));
        *(unsigned short*)(sm + (size_t)(u16 + cb + 1) * 16 + jo) = f2bf(__expf(cv[z].y * nie));
        *(unsigned short*)(sm + (size_t)(u16 + cb + 2) * 16 + jo) = f2bf(__expf(cv[z].z * nie));
        *(unsigned short*)(sm + (size_t)(u16 + cb + 3) * 16 + jo) = f2bf(__expf(cv[z].w * nie));
      }
    }
  }

  for (int it = 0; it < NITER; ++it) {
    // ========== phase A: u[n] = alpha[n]/(K v)[n], own 16 rows ==========
    v2f acc01[4] = {}, acc23[4] = {};
    const int r0 = base0 + wave * 4;
    const uint4* Kr0 = (const uint4*)(K + (size_t)r0 * NN);
#pragma unroll 1
    for (int q = 0; q < 4; ++q) {
      {
        float4* L = (float4*)(sm + STG_OFF);
        int s0 = t * 4;
        if (it == 0) {
          float4 one = make_float4(1.f, 1.f, 1.f, 1.f);
#pragma unroll
          for (int e = 0; e < 4; ++e) {
            int s = s0 + e;
            L[s ^ ((s >> 3) & 7)] = one;
          }
        } else {
          const unsigned long long* P = v_ep + (size_t)(it - 1) * NN + q * 1024 + t * 4;
          unsigned long long a0, a1, a2, a3;
          for (;;) {                     // dataflow wait on v epoch
            a0 = aload8(P); a1 = aload8(P + 1);
            a2 = aload8(P + 2); a3 = aload8(P + 3);
            if (!(bad8(a0) || bad8(a1) || bad8(a2) || bad8(a3))) break;
            __builtin_amdgcn_s_sleep(1);
          }
          float4 f0 = up4((unsigned)a0, (unsigned)(a0 >> 32));
          float4 f1 = up4((unsigned)a1, (unsigned)(a1 >> 32));
          float4 f2 = up4((unsigned)a2, (unsigned)(a2 >> 32));
          float4 f3 = up4((unsigned)a3, (unsigned)(a3 >> 32));
          L[(s0 + 0) ^ (((s0 + 0) >> 3) & 7)] = f0;
          L[(s0 + 1) ^ (((s0 + 1) >> 3) & 7)] = f1;
          L[(s0 + 2) ^ (((s0 + 2) >> 3) & 7)] = f2;
          L[(s0 + 3) ^ (((s0 + 3) >> 3) & 7)] = f3;
        }
      }
      __syncthreads();
      uint4 karr[8];
#pragma unroll
      for (int ms = 0; ms < 2; ++ms) {
        int moff = q * 128 + ms * 64 + lane;
        karr[ms * 4 + 0] = Kr0[moff];
        karr[ms * 4 + 1] = Kr0[moff + 512];
        karr[ms * 4 + 2] = Kr0[moff + 1024];
        karr[ms * 4 + 3] = Kr0[moff + 1536];
      }
      const float4* VL = (const float4*)(sm + STG_OFF);
#pragma unroll
      for (int ms = 0; ms < 2; ++ms) {
        int mb = ms * 512 + lane * 8;
        float4 vv[8];
#pragma unroll
        for (int j = 0; j < 8; ++j) vv[j] = VL[mb + (j ^ sw)];
#pragma unroll
        for (int r = 0; r < 4; ++r) {
          unsigned int cw[4] = {karr[ms*4+r].x, karr[ms*4+r].y,
                                karr[ms*4+r].z, karr[ms*4+r].w};
#pragma unroll
          for (int w = 0; w < 4; ++w) {
            float2 f = unpk(cw[w]);
            float4 va = vv[2 * w], vb = vv[2 * w + 1];
            acc01[r] = FMA2(mk2(f.x, f.x), mk2(va.x, va.y), acc01[r]);
            acc23[r] = FMA2(mk2(f.x, f.x), mk2(va.z, va.w), acc23[r]);
            acc01[r] = FMA2(mk2(f.y, f.y), mk2(vb.x, vb.y), acc01[r]);
            acc23[r] = FMA2(mk2(f.y, f.y), mk2(vb.z, vb.w), acc23[r]);
          }
        }
      }
      __syncthreads();
    }
    float accf[4][4];
#pragma unroll
    for (int r = 0; r < 4; ++r) {
      accf[r][0] = acc01[r].x; accf[r][1] = acc01[r].y;
      accf[r][2] = acc23[r].x; accf[r][3] = acc23[r].y;
    }
#pragma unroll
    for (int off = 32; off > 0; off >>= 1)
#pragma unroll
      for (int r = 0; r < 4; ++r)
#pragma unroll
        for (int s = 0; s < 4; ++s)
          accf[r][s] += __shfl_xor(accf[r][s], off);
    if (lane < 4) {
      int row = r0 + lane;
      float ux = alpha[0 * NN + row] / accf[lane][0];
      float uy = alpha[1 * NN + row] / accf[lane][1];
      float uz = alpha[2 * NN + row] / accf[lane][2];
      float uw = alpha[3 * NN + row] / accf[lane][3];
      unsigned long long ub = (unsigned long long)pk2(ux, uy) |
                              ((unsigned long long)pk2(uz, uw) << 32);
      astore8(u_ep + (size_t)it * NN + row, ub);   // publish to IC
      if (it == NITER - 1) {
        out[0 * NN + row] = eps * __logf(ux);
        out[1 * NN + row] = eps * __logf(uy);
        out[2 * NN + row] = eps * __logf(uz);
        out[3 * NN + row] = eps * __logf(uw);
      }
    }

    // ========== phase B: v[m] = beta[m]/(K^T u)[m], own 16 cols ==========
    v2f bacc01 = {}, bacc23 = {};
#pragma unroll 1
    for (int q = 0; q < 4; ++q) {
      {
        char* US = sm + STG_OFF;
        const unsigned long long* P = u_ep + (size_t)it * NN + q * 1024 + t * 4;
        unsigned long long a0, a1, a2, a3;
        for (;;) {                       // dataflow wait on u epoch
          a0 = aload8(P); a1 = aload8(P + 1);
          a2 = aload8(P + 2); a3 = aload8(P + 3);
          if (!(bad8(a0) || bad8(a1) || bad8(a2) || bad8(a3))) break;
          __builtin_amdgcn_s_sleep(1);
        }
        float4 f0 = up4((unsigned)a0, (unsigned)(a0 >> 32));
        float4 f1 = up4((unsigned)a1, (unsigned)(a1 >> 32));
        float4 f2 = up4((unsigned)a2, (unsigned)(a2 >> 32));
        float4 f3 = up4((unsigned)a3, (unsigned)(a3 >> 32));
        int n0 = t * 4;                  // pad every 8 slots -> conflict-free
        *(float4*)(US + (n0 + 0) * 16 + ((n0 + 0) >> 3) * 16) = f0;
        *(float4*)(US + (n0 + 1) * 16 + ((n0 + 1) >> 3) * 16) = f1;
        *(float4*)(US + (n0 + 2) * 16 + ((n0 + 2) >> 3) * 16) = f2;
        *(float4*)(US + (n0 + 3) * 16 + ((n0 + 3) >> 3) * 16) = f3;
      }
      __syncthreads();
      const char* US = sm + STG_OFF;
      const int k = t >> 4;
#pragma unroll
      for (int i = 0; i < 8; ++i) {
        uint4 kt = ((const uint4*)sm)[(q * 8 + i) * 256 + t];  // lane-linear
        int nb = k * 64 + i * 8;
        unsigned int kw[4] = {kt.x, kt.y, kt.z, kt.w};
#pragma unroll
        for (int w = 0; w < 4; ++w) {
          float2 f = unpk(kw[w]);
          int j0 = nb + 2 * w, j1 = nb + 2 * w + 1;
          float4 u0 = *(const float4*)(US + j0 * 16 + (j0 >> 3) * 16);
          float4 u1 = *(const float4*)(US + j1 * 16 + (j1 >> 3) * 16);
          bacc01 = FMA2(mk2(f.x, f.x), mk2(u0.x, u0.y), bacc01);
          bacc23 = FMA2(mk2(f.x, f.x), mk2(u0.z, u0.w), bacc23);
          bacc01 = FMA2(mk2(f.y, f.y), mk2(u1.x, u1.y), bacc01);
          bacc23 = FMA2(mk2(f.y, f.y), mk2(u1.z, u1.w), bacc23);
        }
      }
      __syncthreads();
    }
    {
      float4* red = (float4*)(sm + RED_OFF);
      red[(t >> 4) * 16 + (t & 15)] =
          make_float4(bacc01.x, bacc01.y, bacc23.x, bacc23.y);
    }
    __syncthreads();
    if (t < 16) {
      const float4* red = (const float4*)(sm + RED_OFF);
      float4 a = make_float4(0.f, 0.f, 0.f, 0.f);
#pragma unroll
      for (int k2 = 0; k2 < 16; ++k2) {
        float4 r = red[k2 * 16 + t];
        a.x += r.x; a.y += r.y; a.z += r.z; a.w += r.w;
      }
      int m = base0 + t;
      float vx = beta[0 * NN + m] / a.x;
      float vy = beta[1 * NN + m] / a.y;
      float vz = beta[2 * NN + m] / a.z;
      float vw = beta[3 * NN + m] / a.w;
      unsigned long long vb = (unsigned long long)pk2(vx, vy) |
                              ((unsigned long long)pk2(vz, vw) << 32);
      astore8(v_ep + (size_t)it * NN + m, vb);     // publish to IC
      if (it == NITER - 1) {
        out[4 * NN + 0 * NN + m] = eps * __logf(vx);
        out[4 * NN + 1 * NN + m] = eps * __logf(vy);
        out[4 * NN + 2 * NN + m] = eps * __logf(vz);
        out[4 * NN + 3 * NN + m] = eps * __logf(vw);
      }
    }
    __syncthreads();   // red/stage reuse safety before next iteration
  }
}

// ---------------------------------------------------------------------------
extern "C" void kernel_launch(void* const* d_in, const int* in_sizes, int n_in,
                              void* d_out, int out_size, void* d_ws, size_t ws_size,
                              hipStream_t stream) {
  (void)in_sizes; (void)n_in; (void)out_size; (void)ws_size;
  const float* alpha = (const float*)d_in[0];   // f32 (4,4096)
  const float* beta  = (const float*)d_in[1];   // f32 (4,4096)
  const float* C     = (const float*)d_in[2];   // f32 (4096,4096)
  const void*  epsp  = d_in[3];                 // f32 scalar

  char* ws = (char*)d_ws;
  unsigned short* K        = (unsigned short*)ws;                   // 32 MiB
  unsigned long long* u_ep = (unsigned long long*)(ws + 33554432);  // 320 KiB
  unsigned long long* v_ep = (unsigned long long*)(ws + 33554432 + 327680);
  float* out = (float*)d_out;

  // single launch: sync is pure dataflow (epoch sentinels at the IC)
  sinkhorn_all<<<NBLK, 256, 0, stream>>>(alpha, beta, C, epsp, K, u_ep, v_ep,
                                         out);
}

// Round 11
// 266.275 us; speedup vs baseline: 1.1355x; 1.1355x over previous
//
#include <hip/hip_runtime.h>
#include <stdint.h>

#define NN 4096
#define NITER 10
#define ROWS 16
#define NBLK 256
#define THREADS 512

// LDS (bytes): KT interleaved [0,131072) | stage 17408 | red 8192 = 156,672
#define STG_OFF  131072
#define RED_OFF  148480

typedef float v2f __attribute__((ext_vector_type(2)));

static __device__ __forceinline__ unsigned short f2bf(float f) {
  union { float f; unsigned int i; } x; x.f = f;
  unsigned int i = x.i;
  i += 0x7FFFu + ((i >> 16) & 1u);
  return (unsigned short)(i >> 16);
}
static __device__ __forceinline__ unsigned int pk2(float a, float b) {
  return (unsigned int)f2bf(a) | ((unsigned int)f2bf(b) << 16);
}
static __device__ __forceinline__ float2 unpk(unsigned int u) {
  union { unsigned int i; float f; } a, b;
  a.i = u << 16; b.i = u & 0xFFFF0000u;
  return make_float2(a.f, b.f);
}
static __device__ __forceinline__ float read_eps(const void* p) {
  float f = *(const float*)p;
  if (f > 1e-4f && f < 1.0f) return f;
  union { unsigned int i; float f; } x;
  x.i = ((unsigned int)*(const unsigned short*)p) << 16;
  return x.f;
}
static __device__ __forceinline__ void astore8(unsigned long long* p, unsigned long long v) {
  __hip_atomic_store(p, v, __ATOMIC_RELAXED, __HIP_MEMORY_SCOPE_AGENT);
}
static __device__ __forceinline__ float4 up4(unsigned int w0, unsigned int w1) {
  float2 a = unpk(w0), b = unpk(w1);
  return make_float4(a.x, a.y, b.x, b.y);
}
static __device__ __forceinline__ v2f mk2(float a, float b) {
  v2f r; r.x = a; r.y = b; return r;
}
#define FMA2(a, b, c) __builtin_elementwise_fma(a, b, c)

// ws poisoned 0xAA pre-launch -> zero flag arrays stream-ordered.
__global__ __launch_bounds__(256) void zero_flags(unsigned int* __restrict__ c) {
#pragma unroll
  for (int k = 0; k < 32; ++k) c[threadIdx.x + k * 256] = 0;   // 8192 uints
}

// Every wave polls the 64 producer flags of one quarter (1 flag/lane).
// Flags are 64-B strided, written once per block per phase (no RMW, no fences;
// epoch data crosses via IC: writers use agent-scope stores, readers read
// fresh epoch addresses that can't be stale in their L2).
static __device__ __forceinline__ void wait_group(
    const unsigned int* flags, int q, unsigned token) {
  const unsigned int* p = flags + (q * 64 + (threadIdx.x & 63)) * 16;
  for (;;) {
    unsigned v = __hip_atomic_load(p, __ATOMIC_RELAXED,
                                   __HIP_MEMORY_SCOPE_AGENT);
    if (__ballot(v >= token) == 0xFFFFFFFFFFFFFFFFull) break;
    __builtin_amdgcn_s_sleep(1);
  }
}

// ---------------------------------------------------------------------------
// Persistent, 512 thr/block (2 waves/SIMD), block b owns rows/cols
// [16*own, +16) with own = ((b&7)<<5)|(b>>3) (XCD-banded).
// Row-K global+private (L2-resident); col-K^T LDS-resident (lane-linear).
// Sync: per-quarter producer-group flags -> pipelined dataflow, no barriers.
__global__ __launch_bounds__(THREADS, 1) void sinkhorn_all(
    const float* __restrict__ alpha, const float* __restrict__ beta,
    const float* __restrict__ C, const void* __restrict__ epsp,
    unsigned short* __restrict__ K, unsigned long long* __restrict__ u_ep,
    unsigned long long* __restrict__ v_ep, unsigned int* __restrict__ u_flags,
    unsigned int* __restrict__ v_flags, float* __restrict__ out) {
  __shared__ float4 smem4[9792];             // 156,672 B
  char* sm = (char*)smem4;
  const int t = threadIdx.x, b = blockIdx.x;
  const int wave = t >> 6, lane = t & 63;
  const int own = ((b & 7) << 5) | (b >> 3);
  const int base0 = own * ROWS;              // first owned row AND col
  const float eps = read_eps(epsp);
  const float nie = -1.0f / eps;

  // ---- build row-K (global, private): coalesced C row reads ----
#pragma unroll 2
  for (int r = 0; r < ROWS; ++r) {
    const float4* Crow = (const float4*)(C + (size_t)(base0 + r) * NN) + t * 2;
    float4 c0 = Crow[0], c1 = Crow[1];
    uint4 k0;
    k0.x = pk2(__expf(c0.x * nie), __expf(c0.y * nie));
    k0.y = pk2(__expf(c0.z * nie), __expf(c0.w * nie));
    k0.z = pk2(__expf(c1.x * nie), __expf(c1.y * nie));
    k0.w = pk2(__expf(c1.z * nie), __expf(c1.w * nie));
    ((uint4*)(K + (size_t)(base0 + r) * NN))[t] = k0;
  }

  // ---- build K^T strip in LDS (lane-linear interleave) ----
  {
    const int p = t & 3, cb = p * 4, rb = t >> 2;   // rb 0..127
#pragma unroll 1
    for (int q2 = 0; q2 < 32; q2 += 8) {
      float4 cv[8];
#pragma unroll
      for (int z = 0; z < 8; ++z)
        cv[z] = *(const float4*)(C + (size_t)((q2 + z) * 128 + rb) * NN + base0 + cb);
#pragma unroll
      for (int z = 0; z < 8; ++z) {
        int n = (q2 + z) * 128 + rb;
        int u16 = ((n >> 10) * 8 + ((n >> 3) & 7)) * 256 + ((n >> 6) & 15) * 16;
        int jo = (n & 7) * 2;
        *(unsigned short*)(sm + (size_t)(u16 + cb + 0) * 16 + jo) = f2bf(__expf(cv[z].x * nie));
        *(unsigned short*)(sm + (size_t)(u16 + cb + 1) * 16 + jo) = f2bf(__expf(cv[z].y * nie));
        *(unsigned short*)(sm + (size_t)(u16 + cb + 2) * 16 + jo) = f2bf(__expf(cv[z].z * nie));
        *(unsigned short*)(sm + (size_t)(u16 + cb + 3) * 16 + jo) = f2bf(__expf(cv[z].w * nie));
      }
    }
  }
  __syncthreads();

  for (int it = 0; it < NITER; ++it) {
    // ========== phase A: u[n] = alpha[n]/(K v)[n], own 16 rows ==========
    // wave handles 2 rows; staging transposed: slot(m') = (m'&7)*128+(m'>>3)
    v2f acc01[2] = {}, acc23[2] = {};
    const int r0 = base0 + wave * 2;
    const uint4* Kr0 = (const uint4*)(K + (size_t)r0 * NN);
    const uint4* VB = (const uint4*)(v_ep + (size_t)(it - 1) * NN);
#pragma unroll 1
    for (int q = 0; q < 4; ++q) {
      if (it > 0) wait_group(v_flags, q, (unsigned)it);   // per-wave poll
      {
        float4* L = (float4*)(sm + STG_OFF);
        int s0 = t * 2;
        float4 f0, f1;
        if (it == 0) {
          f0 = f1 = make_float4(1.f, 1.f, 1.f, 1.f);
        } else {
          uint4 sv = VB[q * 512 + t];
          f0 = up4(sv.x, sv.y);
          f1 = up4(sv.z, sv.w);
        }
        L[((s0 & 7) * 128) + (s0 >> 3)] = f0;
        L[(((s0 + 1) & 7) * 128) + ((s0 + 1) >> 3)] = f1;
      }
      __syncthreads();
      uint4 karr[4];
#pragma unroll
      for (int ms = 0; ms < 2; ++ms) {
        int moff = q * 128 + ms * 64 + lane;
        karr[ms * 2 + 0] = Kr0[moff];
        karr[ms * 2 + 1] = Kr0[moff + 512];
      }
      const float4* VL = (const float4*)(sm + STG_OFF);
#pragma unroll
      for (int ms = 0; ms < 2; ++ms) {
        int lb = ms * 64 + lane;
        float4 vv[8];
#pragma unroll
        for (int j = 0; j < 8; ++j) vv[j] = VL[j * 128 + lb];  // lane-linear
#pragma unroll
        for (int rr = 0; rr < 2; ++rr) {
          unsigned int cw[4] = {karr[ms*2+rr].x, karr[ms*2+rr].y,
                                karr[ms*2+rr].z, karr[ms*2+rr].w};
#pragma unroll
          for (int w = 0; w < 4; ++w) {
            float2 f = unpk(cw[w]);
            float4 va = vv[2 * w], vb = vv[2 * w + 1];
            acc01[rr] = FMA2(mk2(f.x, f.x), mk2(va.x, va.y), acc01[rr]);
            acc23[rr] = FMA2(mk2(f.x, f.x), mk2(va.z, va.w), acc23[rr]);
            acc01[rr] = FMA2(mk2(f.y, f.y), mk2(vb.x, vb.y), acc01[rr]);
            acc23[rr] = FMA2(mk2(f.y, f.y), mk2(vb.z, vb.w), acc23[rr]);
          }
        }
      }
      __syncthreads();
    }
    float accf[2][4];
#pragma unroll
    for (int rr = 0; rr < 2; ++rr) {
      accf[rr][0] = acc01[rr].x; accf[rr][1] = acc01[rr].y;
      accf[rr][2] = acc23[rr].x; accf[rr][3] = acc23[rr].y;
    }
#pragma unroll
    for (int off = 32; off > 0; off >>= 1)
#pragma unroll
      for (int rr = 0; rr < 2; ++rr)
#pragma unroll
        for (int s = 0; s < 4; ++s)
          accf[rr][s] += __shfl_xor(accf[rr][s], off);
    if (lane < 2) {
      int row = r0 + lane;
      float ux = alpha[0 * NN + row] / accf[lane][0];
      float uy = alpha[1 * NN + row] / accf[lane][1];
      float uz = alpha[2 * NN + row] / accf[lane][2];
      float uw = alpha[3 * NN + row] / accf[lane][3];
      unsigned long long ub = (unsigned long long)pk2(ux, uy) |
                              ((unsigned long long)pk2(uz, uw) << 32);
      astore8(u_ep + (size_t)it * NN + row, ub);
      if (it == NITER - 1) {
        out[0 * NN + row] = eps * __logf(ux);
        out[1 * NN + row] = eps * __logf(uy);
        out[2 * NN + row] = eps * __logf(uz);
        out[3 * NN + row] = eps * __logf(uw);
      }
    }
    __syncthreads();   // all u stores drained (vmcnt) before flag publish
    if (t == 0)
      __hip_atomic_store(u_flags + own * 16, (unsigned)(it + 1),
                         __ATOMIC_RELAXED, __HIP_MEMORY_SCOPE_AGENT);

    // ========== phase B: v[m] = beta[m]/(K^T u)[m], own 16 cols ==========
    v2f bacc01 = {}, bacc23 = {};
    const int c = t & 15, k2 = (t >> 4) & 15, half = t >> 8;
    const uint4* UB = (const uint4*)(u_ep + (size_t)it * NN);
#pragma unroll 1
    for (int q = 0; q < 4; ++q) {
      wait_group(u_flags, q, (unsigned)(it + 1));   // per-wave poll
      {
        char* US = sm + STG_OFF;
        uint4 su = UB[q * 512 + t];
        float4 f0 = up4(su.x, su.y), f1 = up4(su.z, su.w);
        int n0 = t * 2;                 // pad every 16 slots -> 2-way max
        *(float4*)(US + (n0 + 0) * 16 + ((n0 + 0) >> 4) * 16) = f0;
        *(float4*)(US + (n0 + 1) * 16 + ((n0 + 1) >> 4) * 16) = f1;
      }
      __syncthreads();
      const char* US = sm + STG_OFF;
#pragma unroll
      for (int i = 0; i < 4; ++i) {
        uint4 kt = ((const uint4*)sm)[(q * 8 + half * 4 + i) * 256 + k2 * 16 + c];
        int nb = k2 * 64 + (half * 4 + i) * 8;
        unsigned int kw[4] = {kt.x, kt.y, kt.z, kt.w};
#pragma unroll
        for (int w = 0; w < 4; ++w) {
          float2 f = unpk(kw[w]);
          int j0 = nb + 2 * w, j1 = nb + 2 * w + 1;
          float4 u0 = *(const float4*)(US + j0 * 16 + (j0 >> 4) * 16);
          float4 u1 = *(const float4*)(US + j1 * 16 + (j1 >> 4) * 16);
          bacc01 = FMA2(mk2(f.x, f.x), mk2(u0.x, u0.y), bacc01);
          bacc23 = FMA2(mk2(f.x, f.x), mk2(u0.z, u0.w), bacc23);
          bacc01 = FMA2(mk2(f.y, f.y), mk2(u1.x, u1.y), bacc01);
          bacc23 = FMA2(mk2(f.y, f.y), mk2(u1.z, u1.w), bacc23);
        }
      }
      __syncthreads();
    }
    {
      float4* red = (float4*)(sm + RED_OFF);
      red[(half * 16 + k2) * 16 + c] =
          make_float4(bacc01.x, bacc01.y, bacc23.x, bacc23.y);
    }
    __syncthreads();
    if (t < 16) {
      const float4* red = (const float4*)(sm + RED_OFF);
      float4 a = make_float4(0.f, 0.f, 0.f, 0.f);
#pragma unroll
      for (int g = 0; g < 32; ++g) {
        float4 r = red[g * 16 + t];
        a.x += r.x; a.y += r.y; a.z += r.z; a.w += r.w;
      }
      int m = base0 + t;
      float vx = beta[0 * NN + m] / a.x;
      float vy = beta[1 * NN + m] / a.y;
      float vz = beta[2 * NN + m] / a.z;
      float vw = beta[3 * NN + m] / a.w;
      unsigned long long vb = (unsigned long long)pk2(vx, vy) |
                              ((unsigned long long)pk2(vz, vw) << 32);
      astore8(v_ep + (size_t)it * NN + m, vb);
      if (it == NITER - 1) {
        out[4 * NN + 0 * NN + m] = eps * __logf(vx);
        out[4 * NN + 1 * NN + m] = eps * __logf(vy);
        out[4 * NN + 2 * NN + m] = eps * __logf(vz);
        out[4 * NN + 3 * NN + m] = eps * __logf(vw);
      }
    }
    __syncthreads();   // v stores drained before flag publish + LDS reuse
    if (t == 0 && it < NITER - 1)
      __hip_atomic_store(v_flags + own * 16, (unsigned)(it + 1),
                         __ATOMIC_RELAXED, __HIP_MEMORY_SCOPE_AGENT);
  }
}

// ---------------------------------------------------------------------------
extern "C" void kernel_launch(void* const* d_in, const int* in_sizes, int n_in,
                              void* d_out, int out_size, void* d_ws, size_t ws_size,
                              hipStream_t stream) {
  (void)in_sizes; (void)n_in; (void)out_size; (void)ws_size;
  const float* alpha = (const float*)d_in[0];   // f32 (4,4096)
  const float* beta  = (const float*)d_in[1];   // f32 (4,4096)
  const float* C     = (const float*)d_in[2];   // f32 (4096,4096)
  const void*  epsp  = d_in[3];                 // f32 scalar

  char* ws = (char*)d_ws;
  unsigned short* K        = (unsigned short*)ws;                   // 32 MiB
  unsigned long long* u_ep = (unsigned long long*)(ws + 33554432);  // 320 KiB
  unsigned long long* v_ep = (unsigned long long*)(ws + 33554432 + 327680);
  unsigned int* u_flags    = (unsigned int*)(ws + 33554432 + 655360);  // 16 KiB
  unsigned int* v_flags    = (unsigned int*)(ws + 33554432 + 655360 + 16384);
  float* out = (float*)d_out;

  zero_flags<<<1, 256, 0, stream>>>(u_flags);   // zeros u_flags + v_flags
  sinkhorn_all<<<NBLK, THREADS, 0, stream>>>(alpha, beta, C, epsp, K,
                                             u_ep, v_ep, u_flags, v_flags, out);
}